// Round 3
// baseline (36.247 us; speedup 1.0000x reference)
//
#include <hip/hip_runtime.h>

constexpr int BATCH = 4096;
constexpr int DIM   = 2048;
constexpr int REPS  = 8;
constexpr float INV2PI = 0.15915494309189535f;  // 1/(2*pi)

constexpr int TPB   = 256;
constexpr int GRIDX = DIM / TPB;       // 8
constexpr int GRIDY = 256;             // 2048 blocks = 8 blocks/CU exactly
constexpr int BPB   = BATCH / GRIDY;   // 16
constexpr int ILP   = 4;

// Per-d constant tables in d_ws, SoA: tab[k*DIM + d] so lane d reads coalesced.
// k: 0 Xi, 1 Yi, 2 Zi          (initial Bloch state after RZ(t00) and RY(t10) folds)
//    3..10  cy[r], r=1..8      (cos of trainable RY angles)
//    11..18 sy[r], r=1..8
//    19..26 wr[j], j=0..7      (encoding weight / 2pi)
//    27..34 br[j], j=0..7      (encoding bias + next trainable RZ angle, / 2pi)
//    35 pw, 36 pb
constexpr int K_XI = 0, K_YI = 1, K_ZI = 2, K_CY = 3, K_SY = 11,
              K_WR = 19, K_BR = 27, K_PW = 35, K_PB = 36, K_N = 37;

__global__ void daruan_setup(const float* __restrict__ theta,  // (DIM, 9, 2)
                             const float* __restrict__ paw,    // (DIM, 8)
                             const float* __restrict__ pab,    // (DIM, 8)
                             const float* __restrict__ postw,  // (DIM)
                             const float* __restrict__ postb,  // (DIM)
                             float* __restrict__ tab)
{
    const int d = blockIdx.x * blockDim.x + threadIdx.x;
    if (d >= DIM) return;
    const float* th = theta + (size_t)d * (REPS + 1) * 2;

    // H|0> -> Bloch (1,0,0); RZ(t0[0]) -> (cos, sin, 0); then RY(t1[0]) folded in.
    const float t00 = th[0] * INV2PI;
    const float X0  = __builtin_amdgcn_cosf(t00);
    const float Y0  = __builtin_amdgcn_sinf(t00);
    const float t10 = th[1] * INV2PI;
    const float cy0 = __builtin_amdgcn_cosf(t10);
    const float sy0 = __builtin_amdgcn_sinf(t10);
    tab[K_XI * DIM + d] = X0 * cy0;
    tab[K_YI * DIM + d] = Y0;
    tab[K_ZI * DIM + d] = -X0 * sy0;

#pragma unroll
    for (int r = 1; r <= REPS; ++r) {
        const float t1 = th[2 * r + 1] * INV2PI;
        tab[(K_CY + r - 1) * DIM + d] = __builtin_amdgcn_cosf(t1);
        tab[(K_SY + r - 1) * DIM + d] = __builtin_amdgcn_sinf(t1);
    }
#pragma unroll
    for (int j = 0; j < REPS; ++j) {
        tab[(K_WR + j) * DIM + d] = paw[(size_t)d * REPS + j] * INV2PI;
        // fold trainable RZ(theta0[j+1]) (incl. the final one at j=7) into bias
        tab[(K_BR + j) * DIM + d] = (pab[(size_t)d * REPS + j] + th[2 * (j + 1)]) * INV2PI;
    }
    tab[K_PW * DIM + d] = postw[d];
    tab[K_PB * DIM + d] = postb[d];
}

__global__ __launch_bounds__(TPB, 8)
void daruan_main(const float* __restrict__ x,     // (BATCH, DIM)
                 const float* __restrict__ tab,   // (K_N, DIM)
                 float* __restrict__ out)         // (BATCH, DIM)
{
    const int d = blockIdx.x * TPB + threadIdx.x;

    // coalesced, L2-resident table loads
    const float Xi = tab[K_XI * DIM + d];
    const float Yi = tab[K_YI * DIM + d];
    const float Zi = tab[K_ZI * DIM + d];
    float cy[REPS], sy[REPS], wr[REPS], br[REPS];
#pragma unroll
    for (int k = 0; k < REPS; ++k) {
        cy[k] = tab[(K_CY + k) * DIM + d];
        sy[k] = tab[(K_SY + k) * DIM + d];
        wr[k] = tab[(K_WR + k) * DIM + d];
        br[k] = tab[(K_BR + k) * DIM + d];
    }
    const float pw = tab[K_PW * DIM + d];
    const float pb = tab[K_PB * DIM + d];

    const int bbase = blockIdx.y * BPB;

#pragma unroll 1
    for (int bb = 0; bb < BPB; bb += ILP) {
        float xv[ILP];
#pragma unroll
        for (int i = 0; i < ILP; ++i)
            xv[i] = x[(size_t)(bbase + bb + i) * DIM + d];

        float X[ILP], Y[ILP], Z[ILP];

        // r = 0: state is (Xi,Yi,Zi); only the encoded RZ remains (RY folded into init)
#pragma unroll
        for (int i = 0; i < ILP; ++i) {
            const float e  = wr[0] * xv[i] + br[0];
            const float ce = __builtin_amdgcn_cosf(e);
            const float se = __builtin_amdgcn_sinf(e);
            X[i] = Xi * ce - Yi * se;
            Y[i] = Xi * se + Yi * ce;
            Z[i] = Zi;
        }

#pragma unroll
        for (int r = 1; r < REPS; ++r) {
#pragma unroll
            for (int i = 0; i < ILP; ++i) {
                // RY(t1[r])
                const float Xb = X[i] * cy[r - 1] + Z[i] * sy[r - 1];
                const float Zb = Z[i] * cy[r - 1] - X[i] * sy[r - 1];
                // encoded RZ (with next trainable RZ folded in)
                const float e  = wr[r] * xv[i] + br[r];
                const float ce = __builtin_amdgcn_cosf(e);
                const float se = __builtin_amdgcn_sinf(e);
                X[i] = Xb * ce - Y[i] * se;
                if (r < REPS - 1)                      // Y dead after last rep
                    Y[i] = Xb * se + Y[i] * ce;
                Z[i] = Zb;
            }
        }

#pragma unroll
        for (int i = 0; i < ILP; ++i) {
            // final RY (r=8): only Z survives readout
            const float Zf = Z[i] * cy[REPS - 1] - X[i] * sy[REPS - 1];
            out[(size_t)(bbase + bb + i) * DIM + d] = Zf * pw + pb;
        }
    }
}

extern "C" void kernel_launch(void* const* d_in, const int* in_sizes, int n_in,
                              void* d_out, int out_size, void* d_ws, size_t ws_size,
                              hipStream_t stream) {
    const float* x     = (const float*)d_in[0];
    const float* theta = (const float*)d_in[1];
    const float* paw   = (const float*)d_in[2];
    const float* pab   = (const float*)d_in[3];
    const float* postw = (const float*)d_in[4];
    const float* postb = (const float*)d_in[5];
    float* out = (float*)d_out;
    float* tab = (float*)d_ws;   // K_N * DIM floats = 303 KB

    daruan_setup<<<dim3(DIM / 64), dim3(64), 0, stream>>>(theta, paw, pab, postw, postb, tab);
    daruan_main<<<dim3(GRIDX, GRIDY), dim3(TPB), 0, stream>>>(x, tab, out);
}

// Round 4
// 33.026 us; speedup vs baseline: 1.0975x; 1.0975x over previous
//
#include <hip/hip_runtime.h>

constexpr int BATCH = 4096;
constexpr int DIM   = 2048;
constexpr int REPS  = 8;
constexpr float INV2PI = 0.15915494309189535f;  // 1/(2*pi)

constexpr int TPB    = 256;
constexpr int GRIDX  = DIM / TPB;        // 8
constexpr int GRIDY  = 128;              // 1024 blocks = 4 blocks/CU resident
constexpr int BPB    = BATCH / GRIDY;    // 32 batch rows per block
constexpr int ILP    = 8;                // independent chains per thread
constexpr int NCHUNK = BPB / ILP;        // 4

// LDS staging: one reused buffer.
// theta rows are 18 floats -> pitch 19 (gcd(19,32)=1, conflict-free reads)
// paw/pab rows are 8 floats -> pitch 9 (gcd(9,32)=1)
constexpr int TH_PITCH  = 19;
constexpr int PW_PITCH  = 9;
constexpr int LDS_FLOATS = TPB * TH_PITCH;   // 4864 >= 2*TPB*PW_PITCH (4608)

__global__ __launch_bounds__(TPB, 4)
void daruan_kernel(const float* __restrict__ x,       // (BATCH, DIM)
                   const float* __restrict__ theta,   // (DIM, 9, 2)
                   const float* __restrict__ paw,     // (DIM, 8)
                   const float* __restrict__ pab,     // (DIM, 8)
                   const float* __restrict__ postw,   // (DIM)
                   const float* __restrict__ postb,   // (DIM)
                   float* __restrict__ out)           // (BATCH, DIM)
{
    __shared__ float lds[LDS_FLOATS];
    const int t = threadIdx.x;
    const int d = blockIdx.x * TPB + t;

    // ---- phase 1: coalesced stage of this block's theta slice ----
    {
        const float* gth = theta + (size_t)blockIdx.x * TPB * 18;
#pragma unroll
        for (int p = 0; p < 18; ++p) {
            const int idx = p * TPB + t;
            lds[(idx / 18) * TH_PITCH + (idx % 18)] = gth[idx];
        }
    }
    __syncthreads();

    // Algebra: all trainable RZs fold away. RZ(t0[0]) rotates the initial
    // Bloch vector (1,0,0); RY(t1[0]) folds into the initial state too.
    // RZ(t0[r+1]) folds into rep r's encoding bias (Z-rotations commute/add).
    float cy[REPS], sy[REPS], th0n[REPS];
    float Xi, Yi, Zi;
    {
        const float* th_l = lds + t * TH_PITCH;
        const float t00 = th_l[0] * INV2PI;
        const float X0  = __builtin_amdgcn_cosf(t00);
        const float Y0  = __builtin_amdgcn_sinf(t00);
        const float t10 = th_l[1] * INV2PI;
        const float c10 = __builtin_amdgcn_cosf(t10);
        const float s10 = __builtin_amdgcn_sinf(t10);
        Xi = X0 * c10; Yi = Y0; Zi = -X0 * s10;
#pragma unroll
        for (int k = 0; k < REPS; ++k) {
            const float t1 = th_l[2 * k + 3] * INV2PI;   // theta1[k+1]
            cy[k] = __builtin_amdgcn_cosf(t1);
            sy[k] = __builtin_amdgcn_sinf(t1);
            th0n[k] = th_l[2 * k + 2];                   // theta0[k+1]
        }
    }
    __syncthreads();   // done with theta buffer before overwrite

    // ---- phase 2: coalesced stage of paw, pab ----
    {
        const float* gpw = paw + (size_t)blockIdx.x * TPB * REPS;
        const float* gpb = pab + (size_t)blockIdx.x * TPB * REPS;
#pragma unroll
        for (int p = 0; p < 8; ++p) {
            const int idx = p * TPB + t;
            const int row = idx / 8, col = idx % 8;
            lds[row * PW_PITCH + col] = gpw[idx];
            lds[TPB * PW_PITCH + row * PW_PITCH + col] = gpb[idx];
        }
    }
    __syncthreads();

    float wr[REPS], br[REPS];
#pragma unroll
    for (int k = 0; k < REPS; ++k) {
        wr[k] = lds[t * PW_PITCH + k] * INV2PI;
        br[k] = (lds[TPB * PW_PITCH + t * PW_PITCH + k] + th0n[k]) * INV2PI;
    }
    const float pw = postw[d];   // already coalesced in global
    const float pb = postb[d];

    // ---- main loop: 4 chunks x 8-deep ILP, next-chunk x prefetched ----
    const int bbase = blockIdx.y * BPB;
    const float* xp = x + (size_t)bbase * DIM + d;
    float* op = out + (size_t)bbase * DIM + d;

    auto compute_store = [&](const float (&xvv)[ILP], int cc) {
        float X[ILP], Y[ILP], Z[ILP];
#pragma unroll
        for (int i = 0; i < ILP; ++i) {
            const float e  = wr[0] * xvv[i] + br[0];
            const float ce = __builtin_amdgcn_cosf(e);
            const float se = __builtin_amdgcn_sinf(e);
            X[i] = Xi * ce - Yi * se;
            Y[i] = Xi * se + Yi * ce;
            Z[i] = Zi;
        }
#pragma unroll
        for (int r = 1; r < REPS; ++r) {
#pragma unroll
            for (int i = 0; i < ILP; ++i) {
                const float Xb = X[i] * cy[r - 1] + Z[i] * sy[r - 1];
                const float Zb = Z[i] * cy[r - 1] - X[i] * sy[r - 1];
                const float e  = wr[r] * xvv[i] + br[r];
                const float ce = __builtin_amdgcn_cosf(e);
                const float se = __builtin_amdgcn_sinf(e);
                X[i] = Xb * ce - Y[i] * se;
                if (r < REPS - 1)              // Y dead after last rep
                    Y[i] = Xb * se + Y[i] * ce;
                Z[i] = Zb;
            }
        }
#pragma unroll
        for (int i = 0; i < ILP; ++i) {
            const float Zf = Z[i] * cy[REPS - 1] - X[i] * sy[REPS - 1];
            op[(size_t)(cc * ILP + i) * DIM] = Zf * pw + pb;
        }
    };

    float xv[ILP];
#pragma unroll
    for (int i = 0; i < ILP; ++i) xv[i] = xp[(size_t)i * DIM];

#pragma unroll 1
    for (int cc = 0; cc < NCHUNK - 1; ++cc) {
        float xn[ILP];
#pragma unroll
        for (int i = 0; i < ILP; ++i)               // prefetch next chunk
            xn[i] = xp[(size_t)((cc + 1) * ILP + i) * DIM];
        compute_store(xv, cc);
#pragma unroll
        for (int i = 0; i < ILP; ++i) xv[i] = xn[i];
    }
    compute_store(xv, NCHUNK - 1);
}

extern "C" void kernel_launch(void* const* d_in, const int* in_sizes, int n_in,
                              void* d_out, int out_size, void* d_ws, size_t ws_size,
                              hipStream_t stream) {
    const float* x     = (const float*)d_in[0];
    const float* theta = (const float*)d_in[1];
    const float* paw   = (const float*)d_in[2];
    const float* pab   = (const float*)d_in[3];
    const float* postw = (const float*)d_in[4];
    const float* postb = (const float*)d_in[5];
    float* out = (float*)d_out;

    daruan_kernel<<<dim3(GRIDX, GRIDY), dim3(TPB), 0, stream>>>(
        x, theta, paw, pab, postw, postb, out);
}